// Round 1
// baseline (199.766 us; speedup 1.0000x reference)
//
#include <hip/hip_runtime.h>
#include <math.h>

#define Bq 8
#define Nq 325
#define F_INq 32
#define Tq 24
#define Hq 4
#define Cq 32
#define HCq 128
#define KMAX 8

// ---------------- prep: normalize weights, extract neighbor lists ----------------
__global__ __launch_bounds__(64) void prep_kernel(
    const float* __restrict__ iw, const float* __restrict__ ib,
    const float* __restrict__ adj,
    int* __restrict__ nbr_cnt, int* __restrict__ nbr_idx, float* __restrict__ nbr_w) {
  __shared__ float wrow[Nq];
  int i = blockIdx.x;
  int lane = threadIdx.x;
  const float* iwr = iw + (size_t)i * Nq;
  const float* ibr = ib + (size_t)i * Nq;
  const float* ar  = adj + (size_t)i * Nq;
  float sum = 0.f;
  for (int j = lane; j < Nq; j += 64) {
    float basev = ibr[j];
    float w = iwr[j];
    float lo = basev * 0.5f, hi = basev * 1.5f;
    w = fminf(fmaxf(w, lo), hi);   // jnp.clip
    w = fmaxf(w, 0.f);
    float wa = w * ar[j];          // w * adj
    wrow[j] = wa;
    sum += wa;
  }
  #pragma unroll
  for (int off = 32; off >= 1; off >>= 1) sum += __shfl_xor(sum, off, 64);
  if (sum == 0.f) sum = 1e-6f;
  float inv = 1.f / sum;
  __syncthreads();
  if (lane == 0) {
    int cnt = 0;
    for (int j = 0; j < Nq; ++j) {
      if (ar[j] != 0.f) {
        if (cnt < KMAX) {
          nbr_idx[i * KMAX + cnt] = j;
          nbr_w[i * KMAX + cnt]   = wrow[j] * inv;
        }
        cnt++;
      }
    }
    nbr_cnt[i] = cnt < KMAX ? cnt : KMAX;
  }
}

// ---------------- Wh projection + f1/f2 ----------------
__global__ __launch_bounds__(256) void wh_kernel(
    const float* __restrict__ x, const float* __restrict__ Ww,
    const float* __restrict__ Wb, const float* __restrict__ attnw,
    float* __restrict__ Wh, float* __restrict__ f1, float* __restrict__ f2) {
  __shared__ float sW[HCq * 33];       // padded: bank-conflict-free
  __shared__ float sb[HCq], sa1[HCq], sa2[HCq];
  __shared__ float sx[F_INq * Tq];     // 768 floats, x[b,n,f,t]
  int bn = blockIdx.x;
  int b = bn / Nq, n = bn % Nq;
  int tid = threadIdx.x;
  for (int k = tid; k < HCq * F_INq; k += 256) {
    int hc = k >> 5, f = k & 31;
    sW[hc * 33 + f] = Ww[k];
  }
  if (tid < HCq) {
    sb[tid] = Wb[tid];
    int h = tid >> 5, c = tid & 31;
    sa1[tid] = attnw[h * 2 * Cq + c];
    sa2[tid] = attnw[h * 2 * Cq + Cq + c];
  }
  const float* xp = x + (size_t)bn * (F_INq * Tq);
  for (int k = tid; k < F_INq * Tq; k += 256) sx[k] = xp[k];
  __syncthreads();

  int hc = tid & 127;
  int h = hc >> 5;
  const float* wr = &sW[hc * 33];
  float A1 = sa1[hc], A2 = sa2[hc], bias = sb[hc];
  for (int item = tid; item < Tq * HCq; item += 256) {
    int t = item >> 7;               // hc constant per thread
    float acc = bias;
    #pragma unroll
    for (int f = 0; f < F_INq; ++f) acc += sx[f * Tq + t] * wr[f];
    size_t o = ((size_t)(b * Tq + t) * Nq + n);
    Wh[o * HCq + hc] = acc;
    float v1 = acc * A1, v2 = acc * A2;
    #pragma unroll
    for (int off = 16; off >= 1; off >>= 1) {
      v1 += __shfl_down(v1, off, 32);
      v2 += __shfl_down(v2, off, 32);
    }
    if ((tid & 31) == 0) {
      f1[o * Hq + h] = v1;
      f2[o * Hq + h] = v2;
    }
  }
}

// ---------------- S_all[b,t,hc] = sum_n Wh[b,t,n,hc] ----------------
__global__ __launch_bounds__(128) void ssum_kernel(
    const float* __restrict__ Wh, float* __restrict__ S) {
  int bt = blockIdx.x;
  int hc = threadIdx.x;
  const float* p = Wh + (size_t)bt * Nq * HCq + hc;
  float s = 0.f;
  for (int n = 0; n < Nq; ++n) s += p[(size_t)n * HCq];
  S[bt * HCq + hc] = s;
}

// ---------------- sparse softmax attention + output transpose ----------------
__global__ __launch_bounds__(256) void attn_kernel(
    const float* __restrict__ Wh, const float* __restrict__ f1,
    const float* __restrict__ f2, const float* __restrict__ S,
    const int* __restrict__ nbr_cnt, const int* __restrict__ nbr_idx,
    const float* __restrict__ nbr_w, float* __restrict__ out) {
  __shared__ float ot[HCq * 25];   // padded tile [hc][t]
  __shared__ int   s_idx[KMAX];
  __shared__ float s_w[KMAX];
  __shared__ int   s_cnt;
  int bi = blockIdx.x;
  int b = bi / Nq, i = bi % Nq;
  int tid = threadIdx.x;
  if (tid == 0) s_cnt = nbr_cnt[i];
  if (tid < KMAX) { s_idx[tid] = nbr_idx[i * KMAX + tid]; s_w[tid] = nbr_w[i * KMAX + tid]; }
  __syncthreads();
  int cnt = s_cnt;
  int tt = tid >> 7;      // 0/1: which t of the pair
  int hc = tid & 127;
  int h = hc >> 5;
  for (int tp = 0; tp < Tq / 2; ++tp) {
    int t = tp * 2 + tt;
    int bt = b * Tq + t;
    size_t rbase = (size_t)bt * Nq;
    float f1i = f1[(rbase + i) * Hq + h];
    float sv[KMAX];
    float m = 0.f;   // non-neighbor scores are exactly 0 (N-cnt >= 1 of them)
    #pragma unroll
    for (int k = 0; k < KMAX; ++k) {
      float s = 0.f;
      if (k < cnt) {
        int j = s_idx[k];
        float e = f1i + f2[(rbase + j) * Hq + h];
        e = e > 0.f ? e : 0.2f * e;          // leaky_relu(0.2)
        s = e + s_w[k];
        m = fmaxf(m, s);
      }
      sv[k] = s;
    }
    float em = __expf(-m);
    float Z = (float)(Nq - cnt) * em;
    float pk[KMAX];
    #pragma unroll
    for (int k = 0; k < KMAX; ++k) {
      float p = 0.f;
      if (k < cnt) { p = __expf(sv[k] - m); Z += p; }
      pk[k] = p;
    }
    float invZ = 1.f / Z;
    float basep = em * invZ;
    float acc = basep * S[bt * HCq + hc];
    #pragma unroll
    for (int k = 0; k < KMAX; ++k) {
      if (k < cnt) {
        int j = s_idx[k];
        acc += (pk[k] * invZ - basep) * Wh[(rbase + j) * HCq + hc];
      }
    }
    ot[hc * 25 + t] = acc;
  }
  __syncthreads();
  size_t obase = (size_t)bi * (HCq * Tq);
  for (int k2 = tid; k2 < HCq * Tq; k2 += 256) {
    int hc2 = k2 / Tq, t2 = k2 - hc2 * Tq;
    out[obase + k2] = ot[hc2 * 25 + t2];
  }
}

extern "C" void kernel_launch(void* const* d_in, const int* in_sizes, int n_in,
                              void* d_out, int out_size, void* d_ws, size_t ws_size,
                              hipStream_t stream) {
  const float* x     = (const float*)d_in[0];
  const float* Ww    = (const float*)d_in[1];
  const float* Wb    = (const float*)d_in[2];
  const float* attnw = (const float*)d_in[3];
  const float* iw    = (const float*)d_in[4];
  const float* ib    = (const float*)d_in[5];
  const float* adj   = (const float*)d_in[6];
  float* out = (float*)d_out;

  float* ws = (float*)d_ws;
  const size_t WH  = (size_t)Bq * Tq * Nq * HCq;   // 7,987,200
  const size_t NF  = (size_t)Bq * Tq * Nq * Hq;    //   249,600
  float* Wh = ws;
  float* f1 = Wh + WH;
  float* f2 = f1 + NF;
  float* S  = f2 + NF;
  int* nbr_cnt = (int*)(S + (size_t)Bq * Tq * HCq);
  int* nbr_idx = nbr_cnt + Nq;
  float* nbr_w = (float*)(nbr_idx + Nq * KMAX);

  prep_kernel<<<Nq, 64, 0, stream>>>(iw, ib, adj, nbr_cnt, nbr_idx, nbr_w);
  wh_kernel<<<Bq * Nq, 256, 0, stream>>>(x, Ww, Wb, attnw, Wh, f1, f2);
  ssum_kernel<<<Bq * Tq, 128, 0, stream>>>(Wh, S);
  attn_kernel<<<Bq * Nq, 256, 0, stream>>>(Wh, f1, f2, S, nbr_cnt, nbr_idx, nbr_w, out);
}

// Round 2
// 186.119 us; speedup vs baseline: 1.0733x; 1.0733x over previous
//
#include <hip/hip_runtime.h>
#include <math.h>

#define Bq 8
#define Nq 325
#define F_INq 32
#define Tq 24
#define Hq 4
#define Cq 32
#define HCq 128
#define RX 136              // extended rows: 128 Wh + 4 f1 + 4 f2
#define ROWSTR (RX * Tq)    // 3264 floats per (b,n)
#define KMAX 4

#define FMA4S(d, a, s) \
  d.x += a.x * (s); d.y += a.y * (s); d.z += a.z * (s); d.w += a.w * (s)

// ---------------- prep: neighbors (blocks 0..324) + weight pack (block 325) --------
__global__ __launch_bounds__(64) void prep_kernel(
    const float* __restrict__ iw, const float* __restrict__ ib,
    const float* __restrict__ adj, const float* __restrict__ Ww,
    const float* __restrict__ Wb, const float* __restrict__ attnw,
    int* __restrict__ nbr_cnt, int* __restrict__ nbr_idx, float* __restrict__ nbr_w,
    float* __restrict__ WxP, float* __restrict__ bx) {
  int blk = blockIdx.x;
  int lane = threadIdx.x;
  if (blk == Nq) {
    // pack: WxP[p][f][s] = Wx[2p+s][f], rows 128..131 = A1, 132..135 = A2
    for (int o = lane; o < 68 * 64; o += 64) {
      int p = o >> 6, rem = o & 63, f = rem >> 1, s = rem & 1;
      int r = 2 * p + s;
      float v;
      if (r < HCq) {
        v = Ww[r * F_INq + f];
      } else {
        int h = (r - HCq) & 3;
        int c0 = (r < 132) ? 0 : Cq;
        v = 0.f;
        for (int c = 0; c < Cq; ++c)
          v += Ww[(h * Cq + c) * F_INq + f] * attnw[h * 2 * Cq + c0 + c];
      }
      WxP[o] = v;
    }
    for (int r = lane; r < RX; r += 64) {
      float v;
      if (r < HCq) {
        v = Wb[r];
      } else {
        int h = (r - HCq) & 3;
        int c0 = (r < 132) ? 0 : Cq;
        v = 0.f;
        for (int c = 0; c < Cq; ++c) v += Wb[h * Cq + c] * attnw[h * 2 * Cq + c0 + c];
      }
      bx[r] = v;
    }
    return;
  }
  // neighbor extraction for row i = blk
  __shared__ float wrow[Nq];
  int i = blk;
  const float* iwr = iw + (size_t)i * Nq;
  const float* ibr = ib + (size_t)i * Nq;
  const float* ar  = adj + (size_t)i * Nq;
  float sum = 0.f;
  for (int j = lane; j < Nq; j += 64) {
    float basev = ibr[j];
    float w = iwr[j];
    w = fminf(fmaxf(w, basev * 0.5f), basev * 1.5f);
    w = fmaxf(w, 0.f);
    float wa = w * ar[j];
    wrow[j] = wa;
    sum += wa;
  }
  #pragma unroll
  for (int off = 32; off >= 1; off >>= 1) sum += __shfl_xor(sum, off, 64);
  if (sum == 0.f) sum = 1e-6f;
  float inv = 1.f / sum;
  __syncthreads();
  if (lane == 0) {
    #pragma unroll
    for (int k = 0; k < KMAX; ++k) { nbr_idx[i * KMAX + k] = 0; nbr_w[i * KMAX + k] = 0.f; }
    int cnt = 0;
    for (int j = 0; j < Nq; ++j) {
      if (ar[j] != 0.f) {
        if (cnt < KMAX) {
          nbr_idx[i * KMAX + cnt] = j;
          nbr_w[i * KMAX + cnt]   = wrow[j] * inv;
        }
        cnt++;
      }
    }
    nbr_cnt[i] = cnt < KMAX ? cnt : KMAX;
  }
}

// ---------------- extended projection: WhX[b][n][r][t], r in [0,136) ----------------
// thread: pair p = tid%68 (rows 2p, 2p+1), t-chunk tc = tid/68 (8 t's). No LDS.
__global__ __launch_bounds__(256) void wh_kernel(
    const float* __restrict__ x, const float* __restrict__ WxP,
    const float* __restrict__ bx, float* __restrict__ WhX) {
  int bn = blockIdx.x;
  int tid = threadIdx.x;
  if (tid >= 204) return;
  int p = tid % 68;
  int tc = tid / 68;  // 0..2
  const float* xp = x + (size_t)bn * (F_INq * Tq) + tc * 8;
  float4 wrv[16];
  const float4* wp4 = (const float4*)(WxP + p * 64);
  #pragma unroll
  for (int j = 0; j < 16; ++j) wrv[j] = wp4[j];
  float b0 = bx[2 * p], b1 = bx[2 * p + 1];
  float4 a0l = {b0, b0, b0, b0}, a0h = a0l;
  float4 a1l = {b1, b1, b1, b1}, a1h = a1l;
  #pragma unroll
  for (int j = 0; j < 16; ++j) {  // f = 2j, 2j+1
    float4 xa = *(const float4*)(xp + (2 * j) * Tq);
    float4 xb = *(const float4*)(xp + (2 * j) * Tq + 4);
    FMA4S(a0l, xa, wrv[j].x); FMA4S(a0h, xb, wrv[j].x);
    FMA4S(a1l, xa, wrv[j].y); FMA4S(a1h, xb, wrv[j].y);
    float4 xc = *(const float4*)(xp + (2 * j + 1) * Tq);
    float4 xd = *(const float4*)(xp + (2 * j + 1) * Tq + 4);
    FMA4S(a0l, xc, wrv[j].z); FMA4S(a0h, xd, wrv[j].z);
    FMA4S(a1l, xc, wrv[j].w); FMA4S(a1h, xd, wrv[j].w);
  }
  float* outp = WhX + (size_t)bn * ROWSTR + (2 * p) * Tq + tc * 8;
  *(float4*)(outp)          = a0l;
  *(float4*)(outp + 4)      = a0h;
  *(float4*)(outp + Tq)     = a1l;
  *(float4*)(outp + Tq + 4) = a1h;
}

// ---------------- S[b][hc*24+t] = sum_n WhX[b][n][hc][t] (rows 0..127) -------------
__global__ __launch_bounds__(256) void ssum_kernel(
    const float* __restrict__ WhX, float* __restrict__ S) {
  __shared__ float spart[4][64];
  int blk = blockIdx.x;
  int b = blk / 48, ch = blk % 48;
  int lane = threadIdx.x & 63, g = threadIdx.x >> 6;
  const float* base = WhX + (size_t)b * Nq * ROWSTR + ch * 64 + lane;
  float s = 0.f;
  for (int n = g; n < Nq; n += 4) s += base[(size_t)n * ROWSTR];
  spart[g][lane] = s;
  __syncthreads();
  if (g == 0) {
    s = spart[0][lane] + spart[1][lane] + spart[2][lane] + spart[3][lane];
    S[b * (HCq * Tq) + ch * 64 + lane] = s;
  }
}

// ---------------- sparse softmax attention, fully coalesced ----------------
__global__ __launch_bounds__(256) void attn_kernel(
    const float* __restrict__ WhX, const float* __restrict__ S,
    const int* __restrict__ nbr_cnt, const int* __restrict__ nbr_idx,
    const float* __restrict__ nbr_w, float* __restrict__ out) {
  __shared__ float sFi[192];       // rows 128..135 of node i (f1 in [0..95])
  __shared__ float sFj[3][96];     // f2 rows (132..135) of the 3 neighbors
  __shared__ float sbp[96];        // basep[h][t]
  __shared__ float spd[3][96];     // (p_k/Z - basep)[h][t]
  __shared__ int sidx[KMAX];
  __shared__ float sw[KMAX];
  __shared__ int scnt;
  int bi = blockIdx.x;
  int b = bi / Nq, i = bi % Nq;
  int tid = threadIdx.x;
  if (tid == 0) scnt = nbr_cnt[i] < 3 ? nbr_cnt[i] : 3;
  if (tid < KMAX) { sidx[tid] = nbr_idx[i * KMAX + tid]; sw[tid] = nbr_w[i * KMAX + tid]; }
  __syncthreads();
  int cnt = scnt;
  const float* wb = WhX + (size_t)b * Nq * ROWSTR;
  if (tid < 192) sFi[tid] = wb[(size_t)i * ROWSTR + HCq * Tq + tid];
  for (int idx = tid; idx < 3 * 96; idx += 256) {
    int k = idx / 96, r = idx - k * 96;
    sFj[k][r] = wb[(size_t)sidx[k] * ROWSTR + 132 * Tq + r];
  }
  __syncthreads();
  if (tid < 96) {  // (h,t) table
    float f1v = sFi[tid];
    float sv[3];
    float m = 0.f;  // >= N-cnt zero-score entries exist
    #pragma unroll
    for (int k = 0; k < 3; ++k) {
      float s = 0.f;
      if (k < cnt) {
        float e = f1v + sFj[k][tid];
        e = e > 0.f ? e : 0.2f * e;   // leaky_relu 0.2
        s = e + sw[k];
        m = fmaxf(m, s);
      }
      sv[k] = s;
    }
    float em = __expf(-m);
    float Z = (float)(Nq - cnt) * em;
    float pk[3];
    #pragma unroll
    for (int k = 0; k < 3; ++k) {
      float p = 0.f;
      if (k < cnt) { p = __expf(sv[k] - m); Z += p; }
      pk[k] = p;
    }
    float invZ = 1.f / Z;
    float bp = em * invZ;
    sbp[tid] = bp;
    #pragma unroll
    for (int k = 0; k < 3; ++k) spd[k][tid] = (k < cnt) ? pk[k] * invZ - bp : 0.f;
  }
  __syncthreads();
  // phase 2: thread owns (hc, half): 12 consecutive t's → 3 float4 streams
  int hc = tid >> 1, half = tid & 1;
  int h = hc >> 5;
  int toff = h * Tq + half * 12;
  float4 bp4[3], pd4[3][3];
  #pragma unroll
  for (int j = 0; j < 3; ++j) bp4[j] = *(const float4*)(sbp + toff + 4 * j);
  #pragma unroll
  for (int k = 0; k < 3; ++k)
    #pragma unroll
    for (int j = 0; j < 3; ++j) pd4[k][j] = *(const float4*)(&spd[k][toff + 4 * j]);
  int eoff = hc * Tq + half * 12;
  const float* sp = S + b * (HCq * Tq) + eoff;
  float4 o4[3];
  #pragma unroll
  for (int j = 0; j < 3; ++j) {
    float4 s4 = *(const float4*)(sp + 4 * j);
    o4[j].x = bp4[j].x * s4.x; o4[j].y = bp4[j].y * s4.y;
    o4[j].z = bp4[j].z * s4.z; o4[j].w = bp4[j].w * s4.w;
  }
  #pragma unroll
  for (int k = 0; k < 3; ++k) {
    const float* wpk = wb + (size_t)sidx[k] * ROWSTR + eoff;
    #pragma unroll
    for (int j = 0; j < 3; ++j) {
      float4 w4 = *(const float4*)(wpk + 4 * j);
      o4[j].x += pd4[k][j].x * w4.x; o4[j].y += pd4[k][j].y * w4.y;
      o4[j].z += pd4[k][j].z * w4.z; o4[j].w += pd4[k][j].w * w4.w;
    }
  }
  float* op = out + (size_t)bi * (HCq * Tq) + eoff;
  #pragma unroll
  for (int j = 0; j < 3; ++j) *(float4*)(op + 4 * j) = o4[j];
}

extern "C" void kernel_launch(void* const* d_in, const int* in_sizes, int n_in,
                              void* d_out, int out_size, void* d_ws, size_t ws_size,
                              hipStream_t stream) {
  const float* x     = (const float*)d_in[0];
  const float* Ww    = (const float*)d_in[1];
  const float* Wb    = (const float*)d_in[2];
  const float* attnw = (const float*)d_in[3];
  const float* iw    = (const float*)d_in[4];
  const float* ib    = (const float*)d_in[5];
  const float* adj   = (const float*)d_in[6];
  float* out = (float*)d_out;

  float* ws = (float*)d_ws;
  const size_t WHX_SZ = (size_t)Bq * Nq * ROWSTR;   // 8,486,400
  const size_t S_SZ   = (size_t)Bq * HCq * Tq;      // 24,576
  float* WhX = ws;
  float* S   = WhX + WHX_SZ;
  float* WxP = S + S_SZ;
  float* bx  = WxP + 68 * 64;
  int* nbr_cnt = (int*)(bx + RX);
  int* nbr_idx = nbr_cnt + Nq;
  float* nbr_w = (float*)(nbr_idx + Nq * KMAX);

  prep_kernel<<<Nq + 1, 64, 0, stream>>>(iw, ib, adj, Ww, Wb, attnw,
                                         nbr_cnt, nbr_idx, nbr_w, WxP, bx);
  wh_kernel<<<Bq * Nq, 256, 0, stream>>>(x, WxP, bx, WhX);
  ssum_kernel<<<Bq * 48, 256, 0, stream>>>(WhX, S);
  attn_kernel<<<Bq * Nq, 256, 0, stream>>>(WhX, S, nbr_cnt, nbr_idx, nbr_w, out);
}